// Round 14
// baseline (328.465 us; speedup 1.0000x reference)
//
#include <hip/hip_runtime.h>
#include <hip/hip_bf16.h>

// ---------------------------------------------------------------------------
// ResidualAttentionBlock: LN1 -> QKV -> MHA -> out-proj(+x) -> LN2 -> FFN(+x)
// B=4, S=1024, d=1024, H=16, dh=64.
//   - prep_kernel: ln1 + weight transposes + in_project split, ONE dispatch.
//   - QK GEMM (N=2048, split-bf16 x3 MFMA), V GEMM (N=1024, plain) separate.
//   - x2 residual MUST stay fp32 (round-11 fail: FFN coherently amplifies
//     x2 rounding ~256x -> absmax 224).
//   - N=1024 GEMMs: BN=64 tiles (2 blocks/CU). XCD-chunked swizzle everywhere.
//   - Attention: 32x32x16 MFMA flash, swapped QK^T, exp2-domain softmax,
//     permlane32_swap. V read global->register (L2-resident per XCD; no V LDS)
//     -> 32KB LDS, 4 blocks/CU, V loads issued early (T14 issue-early).
// ---------------------------------------------------------------------------

typedef short bf16x8 __attribute__((ext_vector_type(8)));
typedef float f32x4 __attribute__((ext_vector_type(4)));
typedef float f32x16 __attribute__((ext_vector_type(16)));

__device__ __forceinline__ unsigned short f2bf(float f) {
  unsigned int u = __float_as_uint(f);
  unsigned int r = (u + 0x7fffu + ((u >> 16) & 1u)) >> 16;
  return (unsigned short)r;
}
__device__ __forceinline__ float bf2f(unsigned short h) {
  return __uint_as_float(((unsigned int)h) << 16);
}
__device__ __forceinline__ unsigned pack2t(float x, float y) {
  return __builtin_amdgcn_perm(__float_as_uint(y), __float_as_uint(x),
                               0x07060302u);
}
__device__ __forceinline__ float fexp2(float x) {
#if defined(__has_builtin)
#if __has_builtin(__builtin_amdgcn_exp2f)
  return __builtin_amdgcn_exp2f(x);
#else
  return exp2f(x);
#endif
#else
  return exp2f(x);
#endif
}

__device__ __forceinline__ void gld16(const void* g, void* l) {
  __builtin_amdgcn_global_load_lds(
      (const __attribute__((address_space(1))) unsigned int*)g,
      (__attribute__((address_space(3))) unsigned int*)l, 16, 0, 0);
}

#if defined(__has_builtin)
#if __has_builtin(__builtin_amdgcn_permlane32_swap)
#define HAVE_PLSWAP 1
#endif
#endif

__device__ __forceinline__ void plswap(unsigned& a, unsigned& b) {
#ifdef HAVE_PLSWAP
  auto r = __builtin_amdgcn_permlane32_swap(a, b, 0, 0);
  a = r[0];
  b = r[1];
#else
  unsigned ta = (unsigned)__shfl_xor((int)a, 32);
  unsigned tb = (unsigned)__shfl_xor((int)b, 32);
  bool hi = (threadIdx.x & 32) != 0;
  unsigned na = hi ? tb : a;
  unsigned nb = hi ? b : ta;
  a = na;
  b = nb;
#endif
}

// ---------------- fused prep: ln1 + transposes + cast_split ----------------
// blocks [0,4096): ln1 rows; [4096,5120): op^T; [5120,7168): wu^T;
// [7168,9216): wd^T; [9216,10240): in_project split (grid-stride).

__global__ __launch_bounds__(256) void prep_kernel(
    const float* __restrict__ x, const float* __restrict__ g1,
    const float* __restrict__ b1, unsigned short* __restrict__ h_hi,
    unsigned short* __restrict__ h_lo, const float* __restrict__ in_project,
    unsigned short* __restrict__ Wq_hi, unsigned short* __restrict__ Wq_lo,
    const float* __restrict__ op, const float* __restrict__ wu,
    const float* __restrict__ wd, unsigned short* __restrict__ oT,
    unsigned short* __restrict__ uT, unsigned short* __restrict__ dT) {
  __shared__ float t[32][33];
  __shared__ float red[8];
  const int blk = blockIdx.x;
  const int tid = threadIdx.x;

  if (blk < 4096) {
    const int row = blk;
    float4 v = ((const float4*)x)[(size_t)row * 256 + tid];
    float s = v.x + v.y + v.z + v.w;
    float ss = v.x * v.x + v.y * v.y + v.z * v.z + v.w * v.w;
#pragma unroll
    for (int off = 32; off; off >>= 1) {
      s += __shfl_xor(s, off);
      ss += __shfl_xor(ss, off);
    }
    int wid = tid >> 6, lane = tid & 63;
    if (lane == 0) { red[wid] = s; red[4 + wid] = ss; }
    __syncthreads();
    s = red[0] + red[1] + red[2] + red[3];
    ss = red[4] + red[5] + red[6] + red[7];
    float mean = s * (1.f / 1024.f);
    float var = ss * (1.f / 1024.f) - mean * mean;
    float inv = rsqrtf(var + 1e-5f);
    float4 g = ((const float4*)g1)[tid];
    float4 bt = ((const float4*)b1)[tid];
    float y[4];
    y[0] = (v.x - mean) * inv * g.x + bt.x;
    y[1] = (v.y - mean) * inv * g.y + bt.y;
    y[2] = (v.z - mean) * inv * g.z + bt.z;
    y[3] = (v.w - mean) * inv * g.w + bt.w;
    size_t o = (size_t)row * 1024 + tid * 4;
#pragma unroll
    for (int j = 0; j < 4; ++j) {
      unsigned short hb = f2bf(y[j]);
      h_hi[o + j] = hb;
      h_lo[o + j] = f2bf(y[j] - bf2f(hb));
    }
  } else if (blk < 9216) {
    const float* in;
    unsigned short* out;
    int R, C, bc, br;
    if (blk < 5120) {
      int i2 = blk - 4096;
      in = op; out = oT; R = 1024; C = 1024;
      bc = (i2 & 31) << 5; br = (i2 >> 5) << 5;
    } else if (blk < 7168) {
      int i2 = blk - 5120;
      in = wu; out = uT; R = 1024; C = 2048;
      bc = (i2 & 63) << 5; br = (i2 >> 6) << 5;
    } else {
      int i2 = blk - 7168;
      in = wd; out = dT; R = 2048; C = 1024;
      bc = (i2 & 31) << 5; br = (i2 >> 5) << 5;
    }
    const int tx = tid & 31, ty = tid >> 5;
#pragma unroll
    for (int i = ty; i < 32; i += 8)
      t[i][tx] = in[(size_t)(br + i) * C + bc + tx];
    __syncthreads();
#pragma unroll
    for (int i = ty; i < 32; i += 8)
      out[(size_t)(bc + i) * R + br + tx] = f2bf(t[tx][i]);
  } else {
    const int n = 3072 * 1024;
    int i = (blk - 9216) * 256 + tid;
    for (; i < n; i += 1024 * 256) {
      float v = in_project[i];
      unsigned short h = f2bf(v);
      Wq_hi[i] = h;
      Wq_lo[i] = f2bf(v - bf2f(h));
    }
  }
}

// ---------------- layernorm 2 (fp32 in, bf16 out) ----------------

__global__ __launch_bounds__(256) void ln2_kernel(
    const float* __restrict__ x, const float* __restrict__ gamma,
    const float* __restrict__ beta, unsigned short* __restrict__ hi) {
  int row = blockIdx.x, tid = threadIdx.x;
  float4 v = ((const float4*)x)[(size_t)row * 256 + tid];
  float s = v.x + v.y + v.z + v.w;
  float ss = v.x * v.x + v.y * v.y + v.z * v.z + v.w * v.w;
#pragma unroll
  for (int off = 32; off; off >>= 1) {
    s += __shfl_xor(s, off);
    ss += __shfl_xor(ss, off);
  }
  __shared__ float red[8];
  int wid = tid >> 6, lane = tid & 63;
  if (lane == 0) { red[wid] = s; red[4 + wid] = ss; }
  __syncthreads();
  s = red[0] + red[1] + red[2] + red[3];
  ss = red[4] + red[5] + red[6] + red[7];
  float mean = s * (1.f / 1024.f);
  float var = ss * (1.f / 1024.f) - mean * mean;
  float inv = rsqrtf(var + 1e-5f);
  float4 g = ((const float4*)gamma)[tid];
  float4 bt = ((const float4*)beta)[tid];
  size_t o = (size_t)row * 1024 + tid * 4;
  hi[o + 0] = f2bf((v.x - mean) * inv * g.x + bt.x);
  hi[o + 1] = f2bf((v.y - mean) * inv * g.y + bt.y);
  hi[o + 2] = f2bf((v.z - mean) * inv * g.z + bt.z);
  hi[o + 3] = f2bf((v.w - mean) * inv * g.w + bt.w);
}

// ---------------- GEMM: C[M,N] = A[M,K] * W[N,K]^T ----------------
// bf16 MFMA 16x16x32, tile 128xBN (BN = BNF*32), BK=32, 4 waves, 2-phase dbuf.
// OUTMODE: 0 normal, 1 QK-split epilogue (N=2048), 2 V-transpose epilogue.
// XCD-chunked bijective block swizzle (requires nwg % 8 == 0).

template <bool SPLIT, bool BIAS, bool RESID, bool RELU, bool OUTBF16,
          int OUTMODE, int BNF>
__global__ __launch_bounds__(256) void gemm_kernel(
    const short* __restrict__ Ah, const short* __restrict__ Al,
    const short* __restrict__ Bh, const short* __restrict__ Bl,
    const float* __restrict__ bias, const float* __restrict__ resid,
    void* __restrict__ outp, int M, int N, int K,
    unsigned short* __restrict__ qh, unsigned short* __restrict__ ql,
    unsigned short* __restrict__ kh, unsigned short* __restrict__ kl,
    unsigned short* __restrict__ vtp) {
  constexpr int BN = BNF * 32;
  __shared__ short As[2][128 * 32];
  __shared__ short Bs[2][BN * 32];
  __shared__ short As2[SPLIT ? 2 : 1][SPLIT ? 128 * 32 : 8];
  __shared__ short Bs2[SPLIT ? 2 : 1][SPLIT ? BN * 32 : 8];

  const int tid = threadIdx.x;
  const int lane = tid & 63;
  const int wid = tid >> 6;
  const int wr = (wid >> 1) << 6;
  const int wc = (wid & 1) * (BNF * 16);
  const int l15 = lane & 15, lh = lane >> 4;

  const int gx = gridDim.x;
  const int lin = blockIdx.y * gx + blockIdx.x;
  const int nwg = gx * gridDim.y;
  const int nl = (lin & 7) * (nwg >> 3) + (lin >> 3);
  const int rowBase = (nl / gx) << 7;
  const int colBase = (nl % gx) * BN;

  const int sr = tid >> 2;
  const int sc = (tid & 3) << 3;
  const int soff = sr * 32 + sc;
  const short* Ag = Ah + (size_t)(rowBase + sr) * K + sc;
  const short* Bg = Bh + (size_t)(colBase + sr) * K + sc;
  const short* Ag2 = SPLIT ? Al + (size_t)(rowBase + sr) * K + sc : nullptr;
  const short* Bg2 = SPLIT ? Bl + (size_t)(colBase + sr) * K + sc : nullptr;

  f32x4 acc[4][BNF];
#pragma unroll
  for (int m = 0; m < 4; ++m)
#pragma unroll
    for (int n = 0; n < BNF; ++n) acc[m][n] = (f32x4){0.f, 0.f, 0.f, 0.f};

  const int kT = K >> 5;
  {
    gld16(Ag, &As[0][soff]);
    gld16(Ag + (size_t)64 * K, &As[0][soff + 64 * 32]);
    gld16(Bg, &Bs[0][soff]);
    if constexpr (BNF == 4) gld16(Bg + (size_t)64 * K, &Bs[0][soff + 64 * 32]);
    if constexpr (SPLIT) {
      gld16(Ag2, &As2[0][soff]);
      gld16(Ag2 + (size_t)64 * K, &As2[0][soff + 64 * 32]);
      gld16(Bg2, &Bs2[0][soff]);
      if constexpr (BNF == 4)
        gld16(Bg2 + (size_t)64 * K, &Bs2[0][soff + 64 * 32]);
    }
  }

  for (int kt = 0; kt < kT; ++kt) {
    __syncthreads();
    const int cb = kt & 1;
    if (kt + 1 < kT) {
      const int nb = cb ^ 1;
      const int k0 = (kt + 1) << 5;
      gld16(Ag + k0, &As[nb][soff]);
      gld16(Ag + k0 + (size_t)64 * K, &As[nb][soff + 64 * 32]);
      gld16(Bg + k0, &Bs[nb][soff]);
      if constexpr (BNF == 4)
        gld16(Bg + k0 + (size_t)64 * K, &Bs[nb][soff + 64 * 32]);
      if constexpr (SPLIT) {
        gld16(Ag2 + k0, &As2[nb][soff]);
        gld16(Ag2 + k0 + (size_t)64 * K, &As2[nb][soff + 64 * 32]);
        gld16(Bg2 + k0, &Bs2[nb][soff]);
        if constexpr (BNF == 4)
          gld16(Bg2 + k0 + (size_t)64 * K, &Bs2[nb][soff + 64 * 32]);
      }
    }

    const short* Asb = As[cb];
    const short* Bsb = Bs[cb];
    bf16x8 af[4], bfr[BNF];
#pragma unroll
    for (int m = 0; m < 4; ++m)
      af[m] = *(const bf16x8*)&Asb[(wr + m * 16 + l15) * 32 + lh * 8];
#pragma unroll
    for (int n = 0; n < BNF; ++n)
      bfr[n] = *(const bf16x8*)&Bsb[(wc + n * 16 + l15) * 32 + lh * 8];
    if constexpr (SPLIT) {
      const short* Asb2 = As2[cb];
      const short* Bsb2 = Bs2[cb];
      bf16x8 af2[4], bfr2[BNF];
#pragma unroll
      for (int m = 0; m < 4; ++m)
        af2[m] = *(const bf16x8*)&Asb2[(wr + m * 16 + l15) * 32 + lh * 8];
#pragma unroll
      for (int n = 0; n < BNF; ++n)
        bfr2[n] = *(const bf16x8*)&Bsb2[(wc + n * 16 + l15) * 32 + lh * 8];
#pragma unroll
      for (int m = 0; m < 4; ++m)
#pragma unroll
        for (int n = 0; n < BNF; ++n) {
          acc[m][n] = __builtin_amdgcn_mfma_f32_16x16x32_bf16(af[m], bfr[n], acc[m][n], 0, 0, 0);
          acc[m][n] = __builtin_amdgcn_mfma_f32_16x16x32_bf16(af[m], bfr2[n], acc[m][n], 0, 0, 0);
          acc[m][n] = __builtin_amdgcn_mfma_f32_16x16x32_bf16(af2[m], bfr[n], acc[m][n], 0, 0, 0);
        }
    } else {
#pragma unroll
      for (int m = 0; m < 4; ++m)
#pragma unroll
        for (int n = 0; n < BNF; ++n)
          acc[m][n] = __builtin_amdgcn_mfma_f32_16x16x32_bf16(af[m], bfr[n], acc[m][n], 0, 0, 0);
    }
  }

  const int prow = rowBase + wr + lh * 4;
  const int pcol = colBase + wc + l15;
#pragma unroll
  for (int m = 0; m < 4; ++m) {
#pragma unroll
    for (int n = 0; n < BNF; ++n) {
      const int c = pcol + n * 16;
      if constexpr (OUTMODE == 2) {
        const int head = c >> 6, dim = c & 63;
        const int r0_ = prow + m * 16;
        const int b = r0_ >> 10, s0 = r0_ & 1023;
        unsigned lo = ((unsigned)f2bf(acc[m][n][1]) << 16) | f2bf(acc[m][n][0]);
        unsigned hi2 = ((unsigned)f2bf(acc[m][n][3]) << 16) | f2bf(acc[m][n][2]);
        unsigned long long wv = ((unsigned long long)hi2 << 32) | lo;
        *(unsigned long long*)&vtp[(((size_t)(b * 16 + head)) * 64 + dim) * 1024 + s0] = wv;
      } else {
        float badd = 0.f;
        if constexpr (BIAS) badd = bias[c];
#pragma unroll
        for (int i = 0; i < 4; ++i) {
          const int r = prow + m * 16 + i;
          float v = acc[m][n][i] + badd;
          if constexpr (OUTMODE == 1) {
            const int part = c >> 10;
            const int cc = c & 1023;
            const int head = cc >> 6, dim = cc & 63;
            const int b = r >> 10, s = r & 1023;
            size_t idx = (((size_t)(b * 16 + head)) * 1024 + s) * 64 + dim;
            if (part == 0) {
              // fold 1/sqrt(dh) * log2(e) into Q -> softmax in exp2 domain
              float y = v * 0.18033688f;
              unsigned short hb = f2bf(y);
              qh[idx] = hb;
              ql[idx] = f2bf(y - bf2f(hb));
            } else {
              unsigned short hb = f2bf(v);
              kh[idx] = hb;
              kl[idx] = f2bf(v - bf2f(hb));
            }
          } else {
            if constexpr (RESID) v += resid[(size_t)r * N + c];
            if constexpr (RELU) v = fmaxf(v, 0.f);
            if constexpr (OUTBF16)
              ((unsigned short*)outp)[(size_t)r * N + c] = f2bf(v);
            else
              ((float*)outp)[(size_t)r * N + c] = v;
          }
        }
      }
    }
  }
}

// ---------------- attention: 32x32x16 MFMA flash, exp2 softmax ----------
// V is read global->register (issued right after the barrier, consumed in PV
// after QK+softmax latency cover); only K(hi,lo) double-buffered in LDS.

__global__ __launch_bounds__(256, 4) void attn_mfma_kernel(
    const short* __restrict__ qhi, const short* __restrict__ qlo,
    const short* __restrict__ khi, const short* __restrict__ klo,
    const short* __restrict__ vt, unsigned short* __restrict__ o,
    int S, int H) {
  __shared__ short Kh[2][64 * 64];
  __shared__ short Kl[2][64 * 64];

  const int tid = threadIdx.x, lane = tid & 63, wid = tid >> 6;
  const int l31 = lane & 31;
  const int hi = lane >> 5;
  const int blk = blockIdx.x;
  const int j = blk >> 3;
  const int bh = ((blk & 7) << 3) + (j & 7);
  const int q0 = (j >> 3) << 7;
  const size_t hbase = (size_t)bh * S * 64;

  const size_t qrow = hbase + (size_t)(q0 + wid * 32 + l31) * 64;
  bf16x8 qfh[4], qfl[4];
#pragma unroll
  for (int t = 0; t < 4; ++t) {
    qfh[t] = *(const bf16x8*)(qhi + qrow + t * 16 + hi * 8);
    qfl[t] = *(const bf16x8*)(qlo + qrow + t * 16 + hi * 8);
  }

  float m_run = -INFINITY, l_run = 0.f;
  f32x16 accO0, accO1;
#pragma unroll
  for (int r = 0; r < 16; ++r) { accO0[r] = 0.f; accO1[r] = 0.f; }

  const int r0 = tid >> 3, c0 = tid & 7;
  const int sw0 = ((c0 ^ (r0 & 7)) << 3);
  const int r1 = r0 + 32;
  const int sw1 = ((c0 ^ (r1 & 7)) << 3);

  const int nT = S >> 6;
  {
    gld16(khi + hbase + r0 * 64 + sw0, (char*)Kh[0] + tid * 16);
    gld16(khi + hbase + r1 * 64 + sw1, (char*)Kh[0] + tid * 16 + 4096);
    gld16(klo + hbase + r0 * 64 + sw0, (char*)Kl[0] + tid * 16);
    gld16(klo + hbase + r1 * 64 + sw1, (char*)Kl[0] + tid * 16 + 4096);
  }

  for (int kt = 0; kt < nT; ++kt) {
    __syncthreads();
    const int cb = kt & 1;

    // V tile for THIS iteration: global->register, issued FIRST so PV's
    // wait can leave the K-staging (issued after) still in flight.
    bf16x8 bv0_[4], bv1_[4];
    {
      const short* vgt = vt + hbase + (size_t)kt * 64;
      const short* vr0 = vgt + (size_t)l31 * 1024 + hi * 8;
      const short* vr1 = vgt + (size_t)(32 + l31) * 1024 + hi * 8;
#pragma unroll
      for (int c = 0; c < 4; ++c) {
        bv0_[c] = *(const bf16x8*)(vr0 + c * 16);
        bv1_[c] = *(const bf16x8*)(vr1 + c * 16);
      }
    }

    if (kt + 1 < nT) {
      const int nb = cb ^ 1;
      const size_t kb = hbase + (size_t)(kt + 1) * 64 * 64;
      gld16(khi + kb + r0 * 64 + sw0, (char*)Kh[nb] + tid * 16);
      gld16(khi + kb + r1 * 64 + sw1, (char*)Kh[nb] + tid * 16 + 4096);
      gld16(klo + kb + r0 * 64 + sw0, (char*)Kl[nb] + tid * 16);
      gld16(klo + kb + r1 * 64 + sw1, (char*)Kl[nb] + tid * 16 + 4096);
    }

    const short* KhB = Kh[cb];
    const short* KlB = Kl[cb];

    // QK with 2-way split accumulator chains
    f32x16 sA, sB, sA2, sB2;
#pragma unroll
    for (int r = 0; r < 16; ++r) { sA[r] = 0.f; sB[r] = 0.f; sA2[r] = 0.f; sB2[r] = 0.f; }
    __builtin_amdgcn_s_setprio(1);
#pragma unroll
    for (int t = 0; t < 4; ++t) {
      const int cA = ((2 * t + hi) ^ (l31 & 7)) << 3;
      bf16x8 kh0 = *(const bf16x8*)&KhB[l31 * 64 + cA];
      bf16x8 kl0 = *(const bf16x8*)&KlB[l31 * 64 + cA];
      bf16x8 kh1 = *(const bf16x8*)&KhB[(32 + l31) * 64 + cA];
      bf16x8 kl1 = *(const bf16x8*)&KlB[(32 + l31) * 64 + cA];
      f32x16& dA = (t < 2) ? sA : sA2;
      f32x16& dB = (t < 2) ? sB : sB2;
      dA = __builtin_amdgcn_mfma_f32_32x32x16_bf16(kh0, qfh[t], dA, 0, 0, 0);
      dB = __builtin_amdgcn_mfma_f32_32x32x16_bf16(kh1, qfh[t], dB, 0, 0, 0);
      dA = __builtin_amdgcn_mfma_f32_32x32x16_bf16(kh0, qfl[t], dA, 0, 0, 0);
      dB = __builtin_amdgcn_mfma_f32_32x32x16_bf16(kh1, qfl[t], dB, 0, 0, 0);
      dA = __builtin_amdgcn_mfma_f32_32x32x16_bf16(kl0, qfh[t], dA, 0, 0, 0);
      dB = __builtin_amdgcn_mfma_f32_32x32x16_bf16(kl1, qfh[t], dB, 0, 0, 0);
    }
    __builtin_amdgcn_s_setprio(0);
#pragma unroll
    for (int r = 0; r < 16; ++r) { sA[r] += sA2[r]; sB[r] += sB2[r]; }

    float t8[8];
#pragma unroll
    for (int r = 0; r < 8; ++r)
      t8[r] = fmaxf(fmaxf(sA[2 * r], sA[2 * r + 1]),
                    fmaxf(sB[2 * r], sB[2 * r + 1]));
    float t4a = fmaxf(t8[0], t8[1]), t4b = fmaxf(t8[2], t8[3]);
    float t4c = fmaxf(t8[4], t8[5]), t4d = fmaxf(t8[6], t8[7]);
    float mt = fmaxf(fmaxf(t4a, t4b), fmaxf(t4c, t4d));
    {
      unsigned ma = __float_as_uint(mt), mb = ma;
      plswap(ma, mb);
      mt = fmaxf(__uint_as_float(ma), __uint_as_float(mb));
    }

    if (__any(mt > m_run + 11.5f)) {
      float mn = fmaxf(m_run, mt);
      float a = fexp2(m_run - mn);
      m_run = mn;
      l_run *= a;
#pragma unroll
      for (int r = 0; r < 16; ++r) {
        const int qq = (r & 3) + 8 * (r >> 2) + 4 * hi;
        float ar = __shfl(a, qq);
        accO0[r] *= ar;
        accO1[r] *= ar;
      }
    }

    float ls = 0.f;
#pragma unroll
    for (int r = 0; r < 16; ++r) {
      sA[r] = fexp2(sA[r] - m_run);
      sB[r] = fexp2(sB[r] - m_run);
      ls += sA[r] + sB[r];
    }
    l_run += ls;

    unsigned a0 = pack2t(sA[0], sA[1]), a1 = pack2t(sA[2], sA[3]);
    unsigned a2 = pack2t(sA[4], sA[5]), a3 = pack2t(sA[6], sA[7]);
    plswap(a0, a2);
    plswap(a1, a3);
    unsigned b0 = pack2t(sA[8], sA[9]), b1 = pack2t(sA[10], sA[11]);
    unsigned b2 = pack2t(sA[12], sA[13]), b3 = pack2t(sA[14], sA[15]);
    plswap(b0, b2);
    plswap(b1, b3);
    unsigned c0_ = pack2t(sB[0], sB[1]), c1_ = pack2t(sB[2], sB[3]);
    unsigned c2_ = pack2t(sB[4], sB[5]), c3_ = pack2t(sB[6], sB[7]);
    plswap(c0_, c2_);
    plswap(c1_, c3_);
    unsigned d0 = pack2t(sB[8], sB[9]), d1 = pack2t(sB[10], sB[11]);
    unsigned d2 = pack2t(sB[12], sB[13]), d3 = pack2t(sB[14], sB[15]);
    plswap(d0, d2);
    plswap(d1, d3);

    bf16x8 pf0, pf1, pf2, pf3;
    {
      unsigned w[4];
      w[0] = a0; w[1] = a1; w[2] = a2; w[3] = a3;
      pf0 = *(bf16x8*)w;
      w[0] = b0; w[1] = b1; w[2] = b2; w[3] = b3;
      pf1 = *(bf16x8*)w;
      w[0] = c0_; w[1] = c1_; w[2] = c2_; w[3] = c3_;
      pf2 = *(bf16x8*)w;
      w[0] = d0; w[1] = d1; w[2] = d2; w[3] = d3;
      pf3 = *(bf16x8*)w;
    }

    __builtin_amdgcn_s_setprio(1);
#pragma unroll
    for (int c = 0; c < 4; ++c) {
      bf16x8 pf = (c == 0) ? pf0 : (c == 1) ? pf1 : (c == 2) ? pf2 : pf3;
      accO0 = __builtin_amdgcn_mfma_f32_32x32x16_bf16(pf, bv0_[c], accO0, 0, 0, 0);
      accO1 = __builtin_amdgcn_mfma_f32_32x32x16_bf16(pf, bv1_[c], accO1, 0, 0, 0);
    }
    __builtin_amdgcn_s_setprio(0);
  }

  {
    unsigned la = __float_as_uint(l_run), lb = la;
    plswap(la, lb);
    l_run = __uint_as_float(la) + __uint_as_float(lb);
  }
  float lrec = 1.0f / l_run;

  const int b = bh >> 4, h = bh & 15;
#pragma unroll
  for (int r = 0; r < 16; ++r) {
    const int qq = (r & 3) + 8 * (r >> 2) + 4 * hi;
    float rr = __shfl(lrec, qq);
    const size_t row = (size_t)(b * S + q0 + wid * 32 + qq) * 1024 + h * 64;
    o[row + l31] = f2bf(accO0[r] * rr);
    o[row + 32 + l31] = f2bf(accO1[r] * rr);
  }
}

// ---------------- launch ----------------

extern "C" void kernel_launch(void* const* d_in, const int* in_sizes, int n_in,
                              void* d_out, int out_size, void* d_ws,
                              size_t ws_size, hipStream_t stream) {
  const float* x = (const float*)d_in[0];
  const float* in_project = (const float*)d_in[1];
  const float* out_project = (const float*)d_in[2];
  const float* ln1_g = (const float*)d_in[3];
  const float* ln1_b = (const float*)d_in[4];
  const float* w_up = (const float*)d_in[5];
  const float* b_up = (const float*)d_in[6];
  const float* w_down = (const float*)d_in[7];
  const float* b_down = (const float*)d_in[8];
  const float* ln2_g = (const float*)d_in[9];
  const float* ln2_b = (const float*)d_in[10];

  const int B = in_sizes[0] / (1024 * 1024);
  const int S = 1024, H = 16;
  const int M = B * S;  // 4096

  char* ws = (char*)d_ws;
  short* h_hi = (short*)(ws + 0);                 // 8MB
  short* h_lo = (short*)(ws + 8388608);           // 8MB
  float* x2 = (float*)(ws + 0);                   // 16MB fp32, reuses h (dead)
  short* qhi = (short*)(ws + 16777216);           // 8MB
  short* qlo = (short*)(ws + 25165824);           // 8MB
  short* khi = (short*)(ws + 33554432);           // 8MB
  short* klo = (short*)(ws + 41943040);           // 8MB
  short* vt  = (short*)(ws + 50331648);           // 8MB
  short* o = (short*)(ws + 67108864);             // 8MB
  short* h2 = (short*)(ws + 75497472);            // 8MB
  short* u = (short*)(ws + 83886080);             // 16MB
  short* Wq_hi = (short*)(ws + 100663296);        // 6MB
  short* Wq_lo = (short*)(ws + 106954752);        // 6MB
  short* WoT = (short*)(ws + 113246208);          // 2MB
  short* WupT = (short*)(ws + 115343360);         // 4MB
  short* WdnT = (short*)(ws + 119537664);         // 4MB

  prep_kernel<<<10240, 256, 0, stream>>>(
      x, ln1_g, ln1_b, (unsigned short*)h_hi, (unsigned short*)h_lo,
      in_project, (unsigned short*)Wq_hi, (unsigned short*)Wq_lo,
      out_project, w_up, w_down, (unsigned short*)WoT, (unsigned short*)WupT,
      (unsigned short*)WdnT);

  // QK GEMM (split x3, N=2048, BN=128) -> q/k split bf16
  gemm_kernel<true, false, false, false, false, 1, 4>
      <<<dim3(2048 / 128, M / 128), 256, 0, stream>>>(
          h_hi, h_lo, Wq_hi, Wq_lo, nullptr, nullptr, nullptr, M, 2048, 1024,
          (unsigned short*)qhi, (unsigned short*)qlo, (unsigned short*)khi,
          (unsigned short*)klo, nullptr);

  // V GEMM (plain, N=1024, BN=64) -> v^T bf16
  gemm_kernel<false, false, false, false, false, 2, 2>
      <<<dim3(1024 / 64, M / 128), 256, 0, stream>>>(
          h_hi, nullptr, Wq_hi + (size_t)2048 * 1024, nullptr, nullptr, nullptr,
          nullptr, M, 1024, 1024, nullptr, nullptr, nullptr, nullptr,
          (unsigned short*)vt);

  attn_mfma_kernel<<<512, 256, 0, stream>>>(
      qhi, qlo, khi, klo, vt, (unsigned short*)o, S, H);

  // out-proj + residual x -> x2 fp32 (BN=64)
  gemm_kernel<false, false, true, false, false, 0, 2>
      <<<dim3(1024 / 64, M / 128), 256, 0, stream>>>(
          o, nullptr, WoT, nullptr, nullptr, x, x2, M, 1024, 1024,
          nullptr, nullptr, nullptr, nullptr, nullptr);

  ln2_kernel<<<M, 256, 0, stream>>>(x2, ln2_g, ln2_b, (unsigned short*)h2);

  // FFN up (BN=128)
  gemm_kernel<false, true, false, true, true, 0, 4>
      <<<dim3(2048 / 128, M / 128), 256, 0, stream>>>(
          h2, nullptr, WupT, nullptr, b_up, nullptr, u, M, 2048, 1024,
          nullptr, nullptr, nullptr, nullptr, nullptr);

  // FFN down + bias + residual x2 -> out fp32 (BN=64)
  gemm_kernel<false, true, true, false, false, 0, 2>
      <<<dim3(1024 / 64, M / 128), 256, 0, stream>>>(
          u, nullptr, WdnT, nullptr, b_down, x2, d_out, M, 1024, 2048,
          nullptr, nullptr, nullptr, nullptr, nullptr);
}

// Round 15
// 227.803 us; speedup vs baseline: 1.4419x; 1.4419x over previous
//
#include <hip/hip_runtime.h>
#include <hip/hip_bf16.h>

// ---------------------------------------------------------------------------
// ResidualAttentionBlock: LN1 -> QKV -> MHA -> out-proj(+x) -> LN2 -> FFN(+x)
// B=4, S=1024, d=1024, H=16, dh=64.
//   - prep_kernel: ln1 + weight transposes + in_project split, ONE dispatch.
//   - QK GEMM (N=2048, split-bf16 x3 MFMA), V GEMM (N=1024, plain) separate.
//   - x2 residual MUST stay fp32 (round-11 fail: FFN coherently amplifies
//     x2 rounding ~256x -> absmax 224).
//   - N=1024 GEMMs: BN=64 tiles (2 blocks/CU). XCD-chunked swizzle everywhere.
//   - Attention: V MUST stay in LDS with 3 blocks/CU (round-14 fail: 4
//     blocks/CU caps VGPR at 64 -> V-in-register spills to scratch, 289MB
//     writes, 3x slower). 32x32x16 MFMA flash, swapped QK^T, exp2 softmax,
//     permlane32_swap redistribution.
// ---------------------------------------------------------------------------

typedef short bf16x8 __attribute__((ext_vector_type(8)));
typedef float f32x4 __attribute__((ext_vector_type(4)));
typedef float f32x16 __attribute__((ext_vector_type(16)));

__device__ __forceinline__ unsigned short f2bf(float f) {
  unsigned int u = __float_as_uint(f);
  unsigned int r = (u + 0x7fffu + ((u >> 16) & 1u)) >> 16;
  return (unsigned short)r;
}
__device__ __forceinline__ float bf2f(unsigned short h) {
  return __uint_as_float(((unsigned int)h) << 16);
}
__device__ __forceinline__ unsigned pack2t(float x, float y) {
  return __builtin_amdgcn_perm(__float_as_uint(y), __float_as_uint(x),
                               0x07060302u);
}
__device__ __forceinline__ float fexp2(float x) {
#if defined(__has_builtin)
#if __has_builtin(__builtin_amdgcn_exp2f)
  return __builtin_amdgcn_exp2f(x);
#else
  return exp2f(x);
#endif
#else
  return exp2f(x);
#endif
}

__device__ __forceinline__ void gld16(const void* g, void* l) {
  __builtin_amdgcn_global_load_lds(
      (const __attribute__((address_space(1))) unsigned int*)g,
      (__attribute__((address_space(3))) unsigned int*)l, 16, 0, 0);
}

#if defined(__has_builtin)
#if __has_builtin(__builtin_amdgcn_permlane32_swap)
#define HAVE_PLSWAP 1
#endif
#endif

__device__ __forceinline__ void plswap(unsigned& a, unsigned& b) {
#ifdef HAVE_PLSWAP
  auto r = __builtin_amdgcn_permlane32_swap(a, b, 0, 0);
  a = r[0];
  b = r[1];
#else
  unsigned ta = (unsigned)__shfl_xor((int)a, 32);
  unsigned tb = (unsigned)__shfl_xor((int)b, 32);
  bool hi = (threadIdx.x & 32) != 0;
  unsigned na = hi ? tb : a;
  unsigned nb = hi ? b : ta;
  a = na;
  b = nb;
#endif
}

// ---------------- fused prep: ln1 + transposes + cast_split ----------------
// blocks [0,4096): ln1 rows; [4096,5120): op^T; [5120,7168): wu^T;
// [7168,9216): wd^T; [9216,10240): in_project split (grid-stride).

__global__ __launch_bounds__(256) void prep_kernel(
    const float* __restrict__ x, const float* __restrict__ g1,
    const float* __restrict__ b1, unsigned short* __restrict__ h_hi,
    unsigned short* __restrict__ h_lo, const float* __restrict__ in_project,
    unsigned short* __restrict__ Wq_hi, unsigned short* __restrict__ Wq_lo,
    const float* __restrict__ op, const float* __restrict__ wu,
    const float* __restrict__ wd, unsigned short* __restrict__ oT,
    unsigned short* __restrict__ uT, unsigned short* __restrict__ dT) {
  __shared__ float t[32][33];
  __shared__ float red[8];
  const int blk = blockIdx.x;
  const int tid = threadIdx.x;

  if (blk < 4096) {
    const int row = blk;
    float4 v = ((const float4*)x)[(size_t)row * 256 + tid];
    float s = v.x + v.y + v.z + v.w;
    float ss = v.x * v.x + v.y * v.y + v.z * v.z + v.w * v.w;
#pragma unroll
    for (int off = 32; off; off >>= 1) {
      s += __shfl_xor(s, off);
      ss += __shfl_xor(ss, off);
    }
    int wid = tid >> 6, lane = tid & 63;
    if (lane == 0) { red[wid] = s; red[4 + wid] = ss; }
    __syncthreads();
    s = red[0] + red[1] + red[2] + red[3];
    ss = red[4] + red[5] + red[6] + red[7];
    float mean = s * (1.f / 1024.f);
    float var = ss * (1.f / 1024.f) - mean * mean;
    float inv = rsqrtf(var + 1e-5f);
    float4 g = ((const float4*)g1)[tid];
    float4 bt = ((const float4*)b1)[tid];
    float y[4];
    y[0] = (v.x - mean) * inv * g.x + bt.x;
    y[1] = (v.y - mean) * inv * g.y + bt.y;
    y[2] = (v.z - mean) * inv * g.z + bt.z;
    y[3] = (v.w - mean) * inv * g.w + bt.w;
    size_t o = (size_t)row * 1024 + tid * 4;
#pragma unroll
    for (int j = 0; j < 4; ++j) {
      unsigned short hb = f2bf(y[j]);
      h_hi[o + j] = hb;
      h_lo[o + j] = f2bf(y[j] - bf2f(hb));
    }
  } else if (blk < 9216) {
    const float* in;
    unsigned short* out;
    int R, C, bc, br;
    if (blk < 5120) {
      int i2 = blk - 4096;
      in = op; out = oT; R = 1024; C = 1024;
      bc = (i2 & 31) << 5; br = (i2 >> 5) << 5;
    } else if (blk < 7168) {
      int i2 = blk - 5120;
      in = wu; out = uT; R = 1024; C = 2048;
      bc = (i2 & 63) << 5; br = (i2 >> 6) << 5;
    } else {
      int i2 = blk - 7168;
      in = wd; out = dT; R = 2048; C = 1024;
      bc = (i2 & 31) << 5; br = (i2 >> 5) << 5;
    }
    const int tx = tid & 31, ty = tid >> 5;
#pragma unroll
    for (int i = ty; i < 32; i += 8)
      t[i][tx] = in[(size_t)(br + i) * C + bc + tx];
    __syncthreads();
#pragma unroll
    for (int i = ty; i < 32; i += 8)
      out[(size_t)(bc + i) * R + br + tx] = f2bf(t[tx][i]);
  } else {
    const int n = 3072 * 1024;
    int i = (blk - 9216) * 256 + tid;
    for (; i < n; i += 1024 * 256) {
      float v = in_project[i];
      unsigned short h = f2bf(v);
      Wq_hi[i] = h;
      Wq_lo[i] = f2bf(v - bf2f(h));
    }
  }
}

// ---------------- layernorm 2 (fp32 in, bf16 out) ----------------

__global__ __launch_bounds__(256) void ln2_kernel(
    const float* __restrict__ x, const float* __restrict__ gamma,
    const float* __restrict__ beta, unsigned short* __restrict__ hi) {
  int row = blockIdx.x, tid = threadIdx.x;
  float4 v = ((const float4*)x)[(size_t)row * 256 + tid];
  float s = v.x + v.y + v.z + v.w;
  float ss = v.x * v.x + v.y * v.y + v.z * v.z + v.w * v.w;
#pragma unroll
  for (int off = 32; off; off >>= 1) {
    s += __shfl_xor(s, off);
    ss += __shfl_xor(ss, off);
  }
  __shared__ float red[8];
  int wid = tid >> 6, lane = tid & 63;
  if (lane == 0) { red[wid] = s; red[4 + wid] = ss; }
  __syncthreads();
  s = red[0] + red[1] + red[2] + red[3];
  ss = red[4] + red[5] + red[6] + red[7];
  float mean = s * (1.f / 1024.f);
  float var = ss * (1.f / 1024.f) - mean * mean;
  float inv = rsqrtf(var + 1e-5f);
  float4 g = ((const float4*)gamma)[tid];
  float4 bt = ((const float4*)beta)[tid];
  size_t o = (size_t)row * 1024 + tid * 4;
  hi[o + 0] = f2bf((v.x - mean) * inv * g.x + bt.x);
  hi[o + 1] = f2bf((v.y - mean) * inv * g.y + bt.y);
  hi[o + 2] = f2bf((v.z - mean) * inv * g.z + bt.z);
  hi[o + 3] = f2bf((v.w - mean) * inv * g.w + bt.w);
}

// ---------------- GEMM: C[M,N] = A[M,K] * W[N,K]^T ----------------
// bf16 MFMA 16x16x32, tile 128xBN (BN = BNF*32), BK=32, 4 waves, 2-phase dbuf.
// OUTMODE: 0 normal, 1 QK-split epilogue (N=2048), 2 V-transpose epilogue.
// XCD-chunked bijective block swizzle (requires nwg % 8 == 0).

template <bool SPLIT, bool BIAS, bool RESID, bool RELU, bool OUTBF16,
          int OUTMODE, int BNF>
__global__ __launch_bounds__(256) void gemm_kernel(
    const short* __restrict__ Ah, const short* __restrict__ Al,
    const short* __restrict__ Bh, const short* __restrict__ Bl,
    const float* __restrict__ bias, const float* __restrict__ resid,
    void* __restrict__ outp, int M, int N, int K,
    unsigned short* __restrict__ qh, unsigned short* __restrict__ ql,
    unsigned short* __restrict__ kh, unsigned short* __restrict__ kl,
    unsigned short* __restrict__ vtp) {
  constexpr int BN = BNF * 32;
  __shared__ short As[2][128 * 32];
  __shared__ short Bs[2][BN * 32];
  __shared__ short As2[SPLIT ? 2 : 1][SPLIT ? 128 * 32 : 8];
  __shared__ short Bs2[SPLIT ? 2 : 1][SPLIT ? BN * 32 : 8];

  const int tid = threadIdx.x;
  const int lane = tid & 63;
  const int wid = tid >> 6;
  const int wr = (wid >> 1) << 6;
  const int wc = (wid & 1) * (BNF * 16);
  const int l15 = lane & 15, lh = lane >> 4;

  const int gx = gridDim.x;
  const int lin = blockIdx.y * gx + blockIdx.x;
  const int nwg = gx * gridDim.y;
  const int nl = (lin & 7) * (nwg >> 3) + (lin >> 3);
  const int rowBase = (nl / gx) << 7;
  const int colBase = (nl % gx) * BN;

  const int sr = tid >> 2;
  const int sc = (tid & 3) << 3;
  const int soff = sr * 32 + sc;
  const short* Ag = Ah + (size_t)(rowBase + sr) * K + sc;
  const short* Bg = Bh + (size_t)(colBase + sr) * K + sc;
  const short* Ag2 = SPLIT ? Al + (size_t)(rowBase + sr) * K + sc : nullptr;
  const short* Bg2 = SPLIT ? Bl + (size_t)(colBase + sr) * K + sc : nullptr;

  f32x4 acc[4][BNF];
#pragma unroll
  for (int m = 0; m < 4; ++m)
#pragma unroll
    for (int n = 0; n < BNF; ++n) acc[m][n] = (f32x4){0.f, 0.f, 0.f, 0.f};

  const int kT = K >> 5;
  {
    gld16(Ag, &As[0][soff]);
    gld16(Ag + (size_t)64 * K, &As[0][soff + 64 * 32]);
    gld16(Bg, &Bs[0][soff]);
    if constexpr (BNF == 4) gld16(Bg + (size_t)64 * K, &Bs[0][soff + 64 * 32]);
    if constexpr (SPLIT) {
      gld16(Ag2, &As2[0][soff]);
      gld16(Ag2 + (size_t)64 * K, &As2[0][soff + 64 * 32]);
      gld16(Bg2, &Bs2[0][soff]);
      if constexpr (BNF == 4)
        gld16(Bg2 + (size_t)64 * K, &Bs2[0][soff + 64 * 32]);
    }
  }

  for (int kt = 0; kt < kT; ++kt) {
    __syncthreads();
    const int cb = kt & 1;
    if (kt + 1 < kT) {
      const int nb = cb ^ 1;
      const int k0 = (kt + 1) << 5;
      gld16(Ag + k0, &As[nb][soff]);
      gld16(Ag + k0 + (size_t)64 * K, &As[nb][soff + 64 * 32]);
      gld16(Bg + k0, &Bs[nb][soff]);
      if constexpr (BNF == 4)
        gld16(Bg + k0 + (size_t)64 * K, &Bs[nb][soff + 64 * 32]);
      if constexpr (SPLIT) {
        gld16(Ag2 + k0, &As2[nb][soff]);
        gld16(Ag2 + k0 + (size_t)64 * K, &As2[nb][soff + 64 * 32]);
        gld16(Bg2 + k0, &Bs2[nb][soff]);
        if constexpr (BNF == 4)
          gld16(Bg2 + k0 + (size_t)64 * K, &Bs2[nb][soff + 64 * 32]);
      }
    }

    const short* Asb = As[cb];
    const short* Bsb = Bs[cb];
    bf16x8 af[4], bfr[BNF];
#pragma unroll
    for (int m = 0; m < 4; ++m)
      af[m] = *(const bf16x8*)&Asb[(wr + m * 16 + l15) * 32 + lh * 8];
#pragma unroll
    for (int n = 0; n < BNF; ++n)
      bfr[n] = *(const bf16x8*)&Bsb[(wc + n * 16 + l15) * 32 + lh * 8];
    if constexpr (SPLIT) {
      const short* Asb2 = As2[cb];
      const short* Bsb2 = Bs2[cb];
      bf16x8 af2[4], bfr2[BNF];
#pragma unroll
      for (int m = 0; m < 4; ++m)
        af2[m] = *(const bf16x8*)&Asb2[(wr + m * 16 + l15) * 32 + lh * 8];
#pragma unroll
      for (int n = 0; n < BNF; ++n)
        bfr2[n] = *(const bf16x8*)&Bsb2[(wc + n * 16 + l15) * 32 + lh * 8];
#pragma unroll
      for (int m = 0; m < 4; ++m)
#pragma unroll
        for (int n = 0; n < BNF; ++n) {
          acc[m][n] = __builtin_amdgcn_mfma_f32_16x16x32_bf16(af[m], bfr[n], acc[m][n], 0, 0, 0);
          acc[m][n] = __builtin_amdgcn_mfma_f32_16x16x32_bf16(af[m], bfr2[n], acc[m][n], 0, 0, 0);
          acc[m][n] = __builtin_amdgcn_mfma_f32_16x16x32_bf16(af2[m], bfr[n], acc[m][n], 0, 0, 0);
        }
    } else {
#pragma unroll
      for (int m = 0; m < 4; ++m)
#pragma unroll
        for (int n = 0; n < BNF; ++n)
          acc[m][n] = __builtin_amdgcn_mfma_f32_16x16x32_bf16(af[m], bfr[n], acc[m][n], 0, 0, 0);
    }
  }

  const int prow = rowBase + wr + lh * 4;
  const int pcol = colBase + wc + l15;
#pragma unroll
  for (int m = 0; m < 4; ++m) {
#pragma unroll
    for (int n = 0; n < BNF; ++n) {
      const int c = pcol + n * 16;
      if constexpr (OUTMODE == 2) {
        const int head = c >> 6, dim = c & 63;
        const int r0_ = prow + m * 16;
        const int b = r0_ >> 10, s0 = r0_ & 1023;
        unsigned lo = ((unsigned)f2bf(acc[m][n][1]) << 16) | f2bf(acc[m][n][0]);
        unsigned hi2 = ((unsigned)f2bf(acc[m][n][3]) << 16) | f2bf(acc[m][n][2]);
        unsigned long long wv = ((unsigned long long)hi2 << 32) | lo;
        *(unsigned long long*)&vtp[(((size_t)(b * 16 + head)) * 64 + dim) * 1024 + s0] = wv;
      } else {
        float badd = 0.f;
        if constexpr (BIAS) badd = bias[c];
#pragma unroll
        for (int i = 0; i < 4; ++i) {
          const int r = prow + m * 16 + i;
          float v = acc[m][n][i] + badd;
          if constexpr (OUTMODE == 1) {
            const int part = c >> 10;
            const int cc = c & 1023;
            const int head = cc >> 6, dim = cc & 63;
            const int b = r >> 10, s = r & 1023;
            size_t idx = (((size_t)(b * 16 + head)) * 1024 + s) * 64 + dim;
            if (part == 0) {
              // fold 1/sqrt(dh) * log2(e) into Q -> softmax in exp2 domain
              float y = v * 0.18033688f;
              unsigned short hb = f2bf(y);
              qh[idx] = hb;
              ql[idx] = f2bf(y - bf2f(hb));
            } else {
              unsigned short hb = f2bf(v);
              kh[idx] = hb;
              kl[idx] = f2bf(v - bf2f(hb));
            }
          } else {
            if constexpr (RESID) v += resid[(size_t)r * N + c];
            if constexpr (RELU) v = fmaxf(v, 0.f);
            if constexpr (OUTBF16)
              ((unsigned short*)outp)[(size_t)r * N + c] = f2bf(v);
            else
              ((float*)outp)[(size_t)r * N + c] = v;
          }
        }
      }
    }
  }
}

// ---------------- attention: 32x32x16 MFMA flash, exp2 softmax ----------
// K(hi,lo) and V double-buffered in LDS (48KB), 3 blocks/CU (VGPR 88, no
// spill). V-in-register at 4 blocks/CU spills (round-14 lesson).

__global__ __launch_bounds__(256, 3) void attn_mfma_kernel(
    const short* __restrict__ qhi, const short* __restrict__ qlo,
    const short* __restrict__ khi, const short* __restrict__ klo,
    const short* __restrict__ vt, unsigned short* __restrict__ o,
    int S, int H) {
  __shared__ short Kh[2][64 * 64];
  __shared__ short Kl[2][64 * 64];
  __shared__ short Vs[2][64 * 64];

  const int tid = threadIdx.x, lane = tid & 63, wid = tid >> 6;
  const int l31 = lane & 31;
  const int hi = lane >> 5;
  const int blk = blockIdx.x;
  const int j = blk >> 3;
  const int bh = ((blk & 7) << 3) + (j & 7);
  const int q0 = (j >> 3) << 7;
  const size_t hbase = (size_t)bh * S * 64;

  const size_t qrow = hbase + (size_t)(q0 + wid * 32 + l31) * 64;
  bf16x8 qfh[4], qfl[4];
#pragma unroll
  for (int t = 0; t < 4; ++t) {
    qfh[t] = *(const bf16x8*)(qhi + qrow + t * 16 + hi * 8);
    qfl[t] = *(const bf16x8*)(qlo + qrow + t * 16 + hi * 8);
  }

  float m_run = -INFINITY, l_run = 0.f;
  f32x16 accO0, accO1;
#pragma unroll
  for (int r = 0; r < 16; ++r) { accO0[r] = 0.f; accO1[r] = 0.f; }

  const int r0 = tid >> 3, c0 = tid & 7;
  const int sw0 = ((c0 ^ (r0 & 7)) << 3);
  const int r1 = r0 + 32;
  const int sw1 = ((c0 ^ (r1 & 7)) << 3);

  const int nT = S >> 6;
  {
    gld16(khi + hbase + r0 * 64 + sw0, (char*)Kh[0] + tid * 16);
    gld16(khi + hbase + r1 * 64 + sw1, (char*)Kh[0] + tid * 16 + 4096);
    gld16(klo + hbase + r0 * 64 + sw0, (char*)Kl[0] + tid * 16);
    gld16(klo + hbase + r1 * 64 + sw1, (char*)Kl[0] + tid * 16 + 4096);
    gld16(vt + hbase + (size_t)r0 * S + sw0, (char*)Vs[0] + tid * 16);
    gld16(vt + hbase + (size_t)r1 * S + sw1, (char*)Vs[0] + tid * 16 + 4096);
  }

  for (int kt = 0; kt < nT; ++kt) {
    __syncthreads();
    const int cb = kt & 1;
    if (kt + 1 < nT) {
      const int nb = cb ^ 1;
      const size_t kb = hbase + (size_t)(kt + 1) * 64 * 64;
      gld16(khi + kb + r0 * 64 + sw0, (char*)Kh[nb] + tid * 16);
      gld16(khi + kb + r1 * 64 + sw1, (char*)Kh[nb] + tid * 16 + 4096);
      gld16(klo + kb + r0 * 64 + sw0, (char*)Kl[nb] + tid * 16);
      gld16(klo + kb + r1 * 64 + sw1, (char*)Kl[nb] + tid * 16 + 4096);
      const short* vg = vt + hbase + (size_t)(kt + 1) * 64;
      gld16(vg + (size_t)r0 * S + sw0, (char*)Vs[nb] + tid * 16);
      gld16(vg + (size_t)r1 * S + sw1, (char*)Vs[nb] + tid * 16 + 4096);
    }

    const short* KhB = Kh[cb];
    const short* KlB = Kl[cb];
    const short* VsB = Vs[cb];

    // QK with 2-way split accumulator chains (t<2 -> sA/sB, t>=2 -> sA2/sB2)
    f32x16 sA, sB, sA2, sB2;
#pragma unroll
    for (int r = 0; r < 16; ++r) { sA[r] = 0.f; sB[r] = 0.f; sA2[r] = 0.f; sB2[r] = 0.f; }
    __builtin_amdgcn_s_setprio(1);
#pragma unroll
    for (int t = 0; t < 4; ++t) {
      const int cA = ((2 * t + hi) ^ (l31 & 7)) << 3;
      bf16x8 kh0 = *(const bf16x8*)&KhB[l31 * 64 + cA];
      bf16x8 kl0 = *(const bf16x8*)&KlB[l31 * 64 + cA];
      bf16x8 kh1 = *(const bf16x8*)&KhB[(32 + l31) * 64 + cA];
      bf16x8 kl1 = *(const bf16x8*)&KlB[(32 + l31) * 64 + cA];
      f32x16& dA = (t < 2) ? sA : sA2;
      f32x16& dB = (t < 2) ? sB : sB2;
      dA = __builtin_amdgcn_mfma_f32_32x32x16_bf16(kh0, qfh[t], dA, 0, 0, 0);
      dB = __builtin_amdgcn_mfma_f32_32x32x16_bf16(kh1, qfh[t], dB, 0, 0, 0);
      dA = __builtin_amdgcn_mfma_f32_32x32x16_bf16(kh0, qfl[t], dA, 0, 0, 0);
      dB = __builtin_amdgcn_mfma_f32_32x32x16_bf16(kh1, qfl[t], dB, 0, 0, 0);
      dA = __builtin_amdgcn_mfma_f32_32x32x16_bf16(kl0, qfh[t], dA, 0, 0, 0);
      dB = __builtin_amdgcn_mfma_f32_32x32x16_bf16(kl1, qfh[t], dB, 0, 0, 0);
    }
    __builtin_amdgcn_s_setprio(0);
#pragma unroll
    for (int r = 0; r < 16; ++r) { sA[r] += sA2[r]; sB[r] += sB2[r]; }

    float t8[8];
#pragma unroll
    for (int r = 0; r < 8; ++r)
      t8[r] = fmaxf(fmaxf(sA[2 * r], sA[2 * r + 1]),
                    fmaxf(sB[2 * r], sB[2 * r + 1]));
    float t4a = fmaxf(t8[0], t8[1]), t4b = fmaxf(t8[2], t8[3]);
    float t4c = fmaxf(t8[4], t8[5]), t4d = fmaxf(t8[6], t8[7]);
    float mt = fmaxf(fmaxf(t4a, t4b), fmaxf(t4c, t4d));
    {
      unsigned ma = __float_as_uint(mt), mb = ma;
      plswap(ma, mb);
      mt = fmaxf(__uint_as_float(ma), __uint_as_float(mb));
    }

    if (__any(mt > m_run + 11.5f)) {
      float mn = fmaxf(m_run, mt);
      float a = fexp2(m_run - mn);
      m_run = mn;
      l_run *= a;
#pragma unroll
      for (int r = 0; r < 16; ++r) {
        const int qq = (r & 3) + 8 * (r >> 2) + 4 * hi;
        float ar = __shfl(a, qq);
        accO0[r] *= ar;
        accO1[r] *= ar;
      }
    }

    float ls = 0.f;
#pragma unroll
    for (int r = 0; r < 16; ++r) {
      sA[r] = fexp2(sA[r] - m_run);
      sB[r] = fexp2(sB[r] - m_run);
      ls += sA[r] + sB[r];
    }
    l_run += ls;

    unsigned a0 = pack2t(sA[0], sA[1]), a1 = pack2t(sA[2], sA[3]);
    unsigned a2 = pack2t(sA[4], sA[5]), a3 = pack2t(sA[6], sA[7]);
    plswap(a0, a2);
    plswap(a1, a3);
    unsigned b0 = pack2t(sA[8], sA[9]), b1 = pack2t(sA[10], sA[11]);
    unsigned b2 = pack2t(sA[12], sA[13]), b3 = pack2t(sA[14], sA[15]);
    plswap(b0, b2);
    plswap(b1, b3);
    unsigned c0_ = pack2t(sB[0], sB[1]), c1_ = pack2t(sB[2], sB[3]);
    unsigned c2_ = pack2t(sB[4], sB[5]), c3_ = pack2t(sB[6], sB[7]);
    plswap(c0_, c2_);
    plswap(c1_, c3_);
    unsigned d0 = pack2t(sB[8], sB[9]), d1 = pack2t(sB[10], sB[11]);
    unsigned d2 = pack2t(sB[12], sB[13]), d3 = pack2t(sB[14], sB[15]);
    plswap(d0, d2);
    plswap(d1, d3);

    bf16x8 pf0, pf1, pf2, pf3;
    {
      unsigned w[4];
      w[0] = a0; w[1] = a1; w[2] = a2; w[3] = a3;
      pf0 = *(bf16x8*)w;
      w[0] = b0; w[1] = b1; w[2] = b2; w[3] = b3;
      pf1 = *(bf16x8*)w;
      w[0] = c0_; w[1] = c1_; w[2] = c2_; w[3] = c3_;
      pf2 = *(bf16x8*)w;
      w[0] = d0; w[1] = d1; w[2] = d2; w[3] = d3;
      pf3 = *(bf16x8*)w;
    }

    __builtin_amdgcn_s_setprio(1);
    {
      const int d1r = 32 + l31;
#pragma unroll
      for (int c = 0; c < 4; ++c) {
        bf16x8 bv0 = *(const bf16x8*)&VsB[l31 * 64 + ((((2 * c + hi)) ^ (l31 & 7)) << 3)];
        bf16x8 bv1 = *(const bf16x8*)&VsB[d1r * 64 + ((((2 * c + hi)) ^ (d1r & 7)) << 3)];
        bf16x8 pf = (c == 0) ? pf0 : (c == 1) ? pf1 : (c == 2) ? pf2 : pf3;
        accO0 = __builtin_amdgcn_mfma_f32_32x32x16_bf16(pf, bv0, accO0, 0, 0, 0);
        accO1 = __builtin_amdgcn_mfma_f32_32x32x16_bf16(pf, bv1, accO1, 0, 0, 0);
      }
    }
    __builtin_amdgcn_s_setprio(0);
  }

  {
    unsigned la = __float_as_uint(l_run), lb = la;
    plswap(la, lb);
    l_run = __uint_as_float(la) + __uint_as_float(lb);
  }
  float lrec = 1.0f / l_run;

  const int b = bh >> 4, h = bh & 15;
#pragma unroll
  for (int r = 0; r < 16; ++r) {
    const int qq = (r & 3) + 8 * (r >> 2) + 4 * hi;
    float rr = __shfl(lrec, qq);
    const size_t row = (size_t)(b * S + q0 + wid * 32 + qq) * 1024 + h * 64;
    o[row + l31] = f2bf(accO0[r] * rr);
    o[row + 32 + l31] = f2bf(accO1[r] * rr);
  }
}

// ---------------- launch ----------------

extern "C" void kernel_launch(void* const* d_in, const int* in_sizes, int n_in,
                              void* d_out, int out_size, void* d_ws,
                              size_t ws_size, hipStream_t stream) {
  const float* x = (const float*)d_in[0];
  const float* in_project = (const float*)d_in[1];
  const float* out_project = (const float*)d_in[2];
  const float* ln1_g = (const float*)d_in[3];
  const float* ln1_b = (const float*)d_in[4];
  const float* w_up = (const float*)d_in[5];
  const float* b_up = (const float*)d_in[6];
  const float* w_down = (const float*)d_in[7];
  const float* b_down = (const float*)d_in[8];
  const float* ln2_g = (const float*)d_in[9];
  const float* ln2_b = (const float*)d_in[10];

  const int B = in_sizes[0] / (1024 * 1024);
  const int S = 1024, H = 16;
  const int M = B * S;  // 4096

  char* ws = (char*)d_ws;
  short* h_hi = (short*)(ws + 0);                 // 8MB
  short* h_lo = (short*)(ws + 8388608);           // 8MB
  float* x2 = (float*)(ws + 0);                   // 16MB fp32, reuses h (dead)
  short* qhi = (short*)(ws + 16777216);           // 8MB
  short* qlo = (short*)(ws + 25165824);           // 8MB
  short* khi = (short*)(ws + 33554432);           // 8MB
  short* klo = (short*)(ws + 41943040);           // 8MB
  short* vt  = (short*)(ws + 50331648);           // 8MB
  short* o = (short*)(ws + 67108864);             // 8MB
  short* h2 = (short*)(ws + 75497472);            // 8MB
  short* u = (short*)(ws + 83886080);             // 16MB
  short* Wq_hi = (short*)(ws + 100663296);        // 6MB
  short* Wq_lo = (short*)(ws + 106954752);        // 6MB
  short* WoT = (short*)(ws + 113246208);          // 2MB
  short* WupT = (short*)(ws + 115343360);         // 4MB
  short* WdnT = (short*)(ws + 119537664);         // 4MB

  prep_kernel<<<10240, 256, 0, stream>>>(
      x, ln1_g, ln1_b, (unsigned short*)h_hi, (unsigned short*)h_lo,
      in_project, (unsigned short*)Wq_hi, (unsigned short*)Wq_lo,
      out_project, w_up, w_down, (unsigned short*)WoT, (unsigned short*)WupT,
      (unsigned short*)WdnT);

  // QK GEMM (split x3, N=2048, BN=128) -> q/k split bf16
  gemm_kernel<true, false, false, false, false, 1, 4>
      <<<dim3(2048 / 128, M / 128), 256, 0, stream>>>(
          h_hi, h_lo, Wq_hi, Wq_lo, nullptr, nullptr, nullptr, M, 2048, 1024,
          (unsigned short*)qhi, (unsigned short*)qlo, (unsigned short*)khi,
          (unsigned short*)klo, nullptr);

  // V GEMM (plain, N=1024, BN=64) -> v^T bf16
  gemm_kernel<false, false, false, false, false, 2, 2>
      <<<dim3(1024 / 64, M / 128), 256, 0, stream>>>(
          h_hi, nullptr, Wq_hi + (size_t)2048 * 1024, nullptr, nullptr, nullptr,
          nullptr, M, 1024, 1024, nullptr, nullptr, nullptr, nullptr,
          (unsigned short*)vt);

  attn_mfma_kernel<<<512, 256, 0, stream>>>(
      qhi, qlo, khi, klo, vt, (unsigned short*)o, S, H);

  // out-proj + residual x -> x2 fp32 (BN=64)
  gemm_kernel<false, false, true, false, false, 0, 2>
      <<<dim3(1024 / 64, M / 128), 256, 0, stream>>>(
          o, nullptr, WoT, nullptr, nullptr, x, x2, M, 1024, 1024,
          nullptr, nullptr, nullptr, nullptr, nullptr);

  ln2_kernel<<<M, 256, 0, stream>>>(x2, ln2_g, ln2_b, (unsigned short*)h2);

  // FFN up (BN=128)
  gemm_kernel<false, true, false, true, true, 0, 4>
      <<<dim3(2048 / 128, M / 128), 256, 0, stream>>>(
          h2, nullptr, WupT, nullptr, b_up, nullptr, u, M, 2048, 1024,
          nullptr, nullptr, nullptr, nullptr, nullptr);

  // FFN down + bias + residual x2 -> out fp32 (BN=64)
  gemm_kernel<false, true, true, false, false, 0, 2>
      <<<dim3(1024 / 64, M / 128), 256, 0, stream>>>(
          u, nullptr, WdnT, nullptr, b_down, x2, d_out, M, 1024, 2048,
          nullptr, nullptr, nullptr, nullptr, nullptr);
}

// Round 16
// 220.422 us; speedup vs baseline: 1.4902x; 1.0335x over previous
//
#include <hip/hip_runtime.h>
#include <hip/hip_bf16.h>

// ---------------------------------------------------------------------------
// ResidualAttentionBlock: LN1 -> QKV -> MHA -> out-proj(+x) -> LN2 -> FFN(+x)
// B=4, S=1024, d=1024, H=16, dh=64.
//   - prep_kernel: ln1 + weight transposes + in_project split, ONE dispatch.
//   - QK GEMM (N=2048, split-bf16 x3 MFMA, 128x128); FFN-up (128x128).
//   - V / out-proj / FFN-down: gemm64_kernel 64x64 tiles -> 1024 blocks
//     (4 blocks/CU; was 2) - latency-bound kernels want occupancy.
//   - x2 residual MUST stay fp32 (round-11: FFN coherently amplifies x2
//     rounding ~256x). Attention V MUST stay in LDS at 3 blocks/CU
//     (round-14: VGPR-64 cap spills 289MB scratch).
//   - Attention: 32x32x16 MFMA flash, swapped QK^T, exp2 softmax,
//     permlane32_swap, XCD-aware grid.
// ---------------------------------------------------------------------------

typedef short bf16x8 __attribute__((ext_vector_type(8)));
typedef float f32x4 __attribute__((ext_vector_type(4)));
typedef float f32x16 __attribute__((ext_vector_type(16)));

__device__ __forceinline__ unsigned short f2bf(float f) {
  unsigned int u = __float_as_uint(f);
  unsigned int r = (u + 0x7fffu + ((u >> 16) & 1u)) >> 16;
  return (unsigned short)r;
}
__device__ __forceinline__ float bf2f(unsigned short h) {
  return __uint_as_float(((unsigned int)h) << 16);
}
__device__ __forceinline__ unsigned pack2t(float x, float y) {
  return __builtin_amdgcn_perm(__float_as_uint(y), __float_as_uint(x),
                               0x07060302u);
}
__device__ __forceinline__ float fexp2(float x) {
#if defined(__has_builtin)
#if __has_builtin(__builtin_amdgcn_exp2f)
  return __builtin_amdgcn_exp2f(x);
#else
  return exp2f(x);
#endif
#else
  return exp2f(x);
#endif
}

__device__ __forceinline__ void gld16(const void* g, void* l) {
  __builtin_amdgcn_global_load_lds(
      (const __attribute__((address_space(1))) unsigned int*)g,
      (__attribute__((address_space(3))) unsigned int*)l, 16, 0, 0);
}

#if defined(__has_builtin)
#if __has_builtin(__builtin_amdgcn_permlane32_swap)
#define HAVE_PLSWAP 1
#endif
#endif

__device__ __forceinline__ void plswap(unsigned& a, unsigned& b) {
#ifdef HAVE_PLSWAP
  auto r = __builtin_amdgcn_permlane32_swap(a, b, 0, 0);
  a = r[0];
  b = r[1];
#else
  unsigned ta = (unsigned)__shfl_xor((int)a, 32);
  unsigned tb = (unsigned)__shfl_xor((int)b, 32);
  bool hi = (threadIdx.x & 32) != 0;
  unsigned na = hi ? tb : a;
  unsigned nb = hi ? b : ta;
  a = na;
  b = nb;
#endif
}

// ---------------- fused prep: ln1 + transposes + cast_split ----------------

__global__ __launch_bounds__(256) void prep_kernel(
    const float* __restrict__ x, const float* __restrict__ g1,
    const float* __restrict__ b1, unsigned short* __restrict__ h_hi,
    unsigned short* __restrict__ h_lo, const float* __restrict__ in_project,
    unsigned short* __restrict__ Wq_hi, unsigned short* __restrict__ Wq_lo,
    const float* __restrict__ op, const float* __restrict__ wu,
    const float* __restrict__ wd, unsigned short* __restrict__ oT,
    unsigned short* __restrict__ uT, unsigned short* __restrict__ dT) {
  __shared__ float t[32][33];
  __shared__ float red[8];
  const int blk = blockIdx.x;
  const int tid = threadIdx.x;

  if (blk < 4096) {
    const int row = blk;
    float4 v = ((const float4*)x)[(size_t)row * 256 + tid];
    float s = v.x + v.y + v.z + v.w;
    float ss = v.x * v.x + v.y * v.y + v.z * v.z + v.w * v.w;
#pragma unroll
    for (int off = 32; off; off >>= 1) {
      s += __shfl_xor(s, off);
      ss += __shfl_xor(ss, off);
    }
    int wid = tid >> 6, lane = tid & 63;
    if (lane == 0) { red[wid] = s; red[4 + wid] = ss; }
    __syncthreads();
    s = red[0] + red[1] + red[2] + red[3];
    ss = red[4] + red[5] + red[6] + red[7];
    float mean = s * (1.f / 1024.f);
    float var = ss * (1.f / 1024.f) - mean * mean;
    float inv = rsqrtf(var + 1e-5f);
    float4 g = ((const float4*)g1)[tid];
    float4 bt = ((const float4*)b1)[tid];
    float y[4];
    y[0] = (v.x - mean) * inv * g.x + bt.x;
    y[1] = (v.y - mean) * inv * g.y + bt.y;
    y[2] = (v.z - mean) * inv * g.z + bt.z;
    y[3] = (v.w - mean) * inv * g.w + bt.w;
    size_t o = (size_t)row * 1024 + tid * 4;
#pragma unroll
    for (int j = 0; j < 4; ++j) {
      unsigned short hb = f2bf(y[j]);
      h_hi[o + j] = hb;
      h_lo[o + j] = f2bf(y[j] - bf2f(hb));
    }
  } else if (blk < 9216) {
    const float* in;
    unsigned short* out;
    int R, C, bc, br;
    if (blk < 5120) {
      int i2 = blk - 4096;
      in = op; out = oT; R = 1024; C = 1024;
      bc = (i2 & 31) << 5; br = (i2 >> 5) << 5;
    } else if (blk < 7168) {
      int i2 = blk - 5120;
      in = wu; out = uT; R = 1024; C = 2048;
      bc = (i2 & 63) << 5; br = (i2 >> 6) << 5;
    } else {
      int i2 = blk - 7168;
      in = wd; out = dT; R = 2048; C = 1024;
      bc = (i2 & 31) << 5; br = (i2 >> 5) << 5;
    }
    const int tx = tid & 31, ty = tid >> 5;
#pragma unroll
    for (int i = ty; i < 32; i += 8)
      t[i][tx] = in[(size_t)(br + i) * C + bc + tx];
    __syncthreads();
#pragma unroll
    for (int i = ty; i < 32; i += 8)
      out[(size_t)(bc + i) * R + br + tx] = f2bf(t[tx][i]);
  } else {
    const int n = 3072 * 1024;
    int i = (blk - 9216) * 256 + tid;
    for (; i < n; i += 1024 * 256) {
      float v = in_project[i];
      unsigned short h = f2bf(v);
      Wq_hi[i] = h;
      Wq_lo[i] = f2bf(v - bf2f(h));
    }
  }
}

// ---------------- layernorm 2 (fp32 in, bf16 out) ----------------

__global__ __launch_bounds__(256) void ln2_kernel(
    const float* __restrict__ x, const float* __restrict__ gamma,
    const float* __restrict__ beta, unsigned short* __restrict__ hi) {
  int row = blockIdx.x, tid = threadIdx.x;
  float4 v = ((const float4*)x)[(size_t)row * 256 + tid];
  float s = v.x + v.y + v.z + v.w;
  float ss = v.x * v.x + v.y * v.y + v.z * v.z + v.w * v.w;
#pragma unroll
  for (int off = 32; off; off >>= 1) {
    s += __shfl_xor(s, off);
    ss += __shfl_xor(ss, off);
  }
  __shared__ float red[8];
  int wid = tid >> 6, lane = tid & 63;
  if (lane == 0) { red[wid] = s; red[4 + wid] = ss; }
  __syncthreads();
  s = red[0] + red[1] + red[2] + red[3];
  ss = red[4] + red[5] + red[6] + red[7];
  float mean = s * (1.f / 1024.f);
  float var = ss * (1.f / 1024.f) - mean * mean;
  float inv = rsqrtf(var + 1e-5f);
  float4 g = ((const float4*)gamma)[tid];
  float4 bt = ((const float4*)beta)[tid];
  size_t o = (size_t)row * 1024 + tid * 4;
  hi[o + 0] = f2bf((v.x - mean) * inv * g.x + bt.x);
  hi[o + 1] = f2bf((v.y - mean) * inv * g.y + bt.y);
  hi[o + 2] = f2bf((v.z - mean) * inv * g.z + bt.z);
  hi[o + 3] = f2bf((v.w - mean) * inv * g.w + bt.w);
}

// ---------------- GEMM 128x128: C[M,N] = A[M,K] * W[N,K]^T ----------------
// bf16 MFMA 16x16x32, BK=32, 4 waves, 2-phase dbuf, XCD-chunked swizzle.
// OUTMODE: 0 normal, 1 QK-split epilogue (N=2048).

template <bool SPLIT, bool BIAS, bool RESID, bool RELU, bool OUTBF16,
          int OUTMODE>
__global__ __launch_bounds__(256) void gemm_kernel(
    const short* __restrict__ Ah, const short* __restrict__ Al,
    const short* __restrict__ Bh, const short* __restrict__ Bl,
    const float* __restrict__ bias, const float* __restrict__ resid,
    void* __restrict__ outp, int M, int N, int K,
    unsigned short* __restrict__ qh, unsigned short* __restrict__ ql,
    unsigned short* __restrict__ kh, unsigned short* __restrict__ kl) {
  __shared__ short As[2][128 * 32];
  __shared__ short Bs[2][128 * 32];
  __shared__ short As2[SPLIT ? 2 : 1][SPLIT ? 128 * 32 : 8];
  __shared__ short Bs2[SPLIT ? 2 : 1][SPLIT ? 128 * 32 : 8];

  const int tid = threadIdx.x;
  const int lane = tid & 63;
  const int wid = tid >> 6;
  const int wr = (wid >> 1) << 6;
  const int wc = (wid & 1) << 6;
  const int l15 = lane & 15, lh = lane >> 4;

  const int gx = gridDim.x;
  const int lin = blockIdx.y * gx + blockIdx.x;
  const int nwg = gx * gridDim.y;
  const int nl = (lin & 7) * (nwg >> 3) + (lin >> 3);
  const int rowBase = (nl / gx) << 7;
  const int colBase = (nl % gx) << 7;

  const int sr = tid >> 2;
  const int sc = (tid & 3) << 3;
  const int soff = sr * 32 + sc;
  const short* Ag = Ah + (size_t)(rowBase + sr) * K + sc;
  const short* Bg = Bh + (size_t)(colBase + sr) * K + sc;
  const short* Ag2 = SPLIT ? Al + (size_t)(rowBase + sr) * K + sc : nullptr;
  const short* Bg2 = SPLIT ? Bl + (size_t)(colBase + sr) * K + sc : nullptr;

  f32x4 acc[4][4];
#pragma unroll
  for (int m = 0; m < 4; ++m)
#pragma unroll
    for (int n = 0; n < 4; ++n) acc[m][n] = (f32x4){0.f, 0.f, 0.f, 0.f};

  const int kT = K >> 5;
  {
    gld16(Ag, &As[0][soff]);
    gld16(Ag + (size_t)64 * K, &As[0][soff + 64 * 32]);
    gld16(Bg, &Bs[0][soff]);
    gld16(Bg + (size_t)64 * K, &Bs[0][soff + 64 * 32]);
    if constexpr (SPLIT) {
      gld16(Ag2, &As2[0][soff]);
      gld16(Ag2 + (size_t)64 * K, &As2[0][soff + 64 * 32]);
      gld16(Bg2, &Bs2[0][soff]);
      gld16(Bg2 + (size_t)64 * K, &Bs2[0][soff + 64 * 32]);
    }
  }

  for (int kt = 0; kt < kT; ++kt) {
    __syncthreads();
    const int cb = kt & 1;
    if (kt + 1 < kT) {
      const int nb = cb ^ 1;
      const int k0 = (kt + 1) << 5;
      gld16(Ag + k0, &As[nb][soff]);
      gld16(Ag + k0 + (size_t)64 * K, &As[nb][soff + 64 * 32]);
      gld16(Bg + k0, &Bs[nb][soff]);
      gld16(Bg + k0 + (size_t)64 * K, &Bs[nb][soff + 64 * 32]);
      if constexpr (SPLIT) {
        gld16(Ag2 + k0, &As2[nb][soff]);
        gld16(Ag2 + k0 + (size_t)64 * K, &As2[nb][soff + 64 * 32]);
        gld16(Bg2 + k0, &Bs2[nb][soff]);
        gld16(Bg2 + k0 + (size_t)64 * K, &Bs2[nb][soff + 64 * 32]);
      }
    }

    const short* Asb = As[cb];
    const short* Bsb = Bs[cb];
    bf16x8 af[4], bfr[4];
#pragma unroll
    for (int m = 0; m < 4; ++m)
      af[m] = *(const bf16x8*)&Asb[(wr + m * 16 + l15) * 32 + lh * 8];
#pragma unroll
    for (int n = 0; n < 4; ++n)
      bfr[n] = *(const bf16x8*)&Bsb[(wc + n * 16 + l15) * 32 + lh * 8];
    if constexpr (SPLIT) {
      const short* Asb2 = As2[cb];
      const short* Bsb2 = Bs2[cb];
      bf16x8 af2[4], bfr2[4];
#pragma unroll
      for (int m = 0; m < 4; ++m)
        af2[m] = *(const bf16x8*)&Asb2[(wr + m * 16 + l15) * 32 + lh * 8];
#pragma unroll
      for (int n = 0; n < 4; ++n)
        bfr2[n] = *(const bf16x8*)&Bsb2[(wc + n * 16 + l15) * 32 + lh * 8];
#pragma unroll
      for (int m = 0; m < 4; ++m)
#pragma unroll
        for (int n = 0; n < 4; ++n) {
          acc[m][n] = __builtin_amdgcn_mfma_f32_16x16x32_bf16(af[m], bfr[n], acc[m][n], 0, 0, 0);
          acc[m][n] = __builtin_amdgcn_mfma_f32_16x16x32_bf16(af[m], bfr2[n], acc[m][n], 0, 0, 0);
          acc[m][n] = __builtin_amdgcn_mfma_f32_16x16x32_bf16(af2[m], bfr[n], acc[m][n], 0, 0, 0);
        }
    } else {
#pragma unroll
      for (int m = 0; m < 4; ++m)
#pragma unroll
        for (int n = 0; n < 4; ++n)
          acc[m][n] = __builtin_amdgcn_mfma_f32_16x16x32_bf16(af[m], bfr[n], acc[m][n], 0, 0, 0);
    }
  }

  const int prow = rowBase + wr + lh * 4;
  const int pcol = colBase + wc + l15;
#pragma unroll
  for (int m = 0; m < 4; ++m) {
#pragma unroll
    for (int n = 0; n < 4; ++n) {
      const int c = pcol + n * 16;
      float badd = 0.f;
      if constexpr (BIAS) badd = bias[c];
#pragma unroll
      for (int i = 0; i < 4; ++i) {
        const int r = prow + m * 16 + i;
        float v = acc[m][n][i] + badd;
        if constexpr (OUTMODE == 1) {
          const int part = c >> 10;
          const int cc = c & 1023;
          const int head = cc >> 6, dim = cc & 63;
          const int b = r >> 10, s = r & 1023;
          size_t idx = (((size_t)(b * 16 + head)) * 1024 + s) * 64 + dim;
          if (part == 0) {
            // fold 1/sqrt(dh) * log2(e) into Q -> softmax in exp2 domain
            float y = v * 0.18033688f;
            unsigned short hb = f2bf(y);
            qh[idx] = hb;
            ql[idx] = f2bf(y - bf2f(hb));
          } else {
            unsigned short hb = f2bf(v);
            kh[idx] = hb;
            kl[idx] = f2bf(v - bf2f(hb));
          }
        } else {
          if constexpr (RESID) v += resid[(size_t)r * N + c];
          if constexpr (RELU) v = fmaxf(v, 0.f);
          if constexpr (OUTBF16)
            ((unsigned short*)outp)[(size_t)r * N + c] = f2bf(v);
          else
            ((float*)outp)[(size_t)r * N + c] = v;
        }
      }
    }
  }
}

// ---------------- GEMM 64x64: latency-friendly (4 blocks/CU) --------------
// 4 waves as 2x2 of 32x32; LDS 16KB dbuf; one gld16/thread/array/K-step.
// OUTMODE: 0 normal, 2 V-transpose epilogue (packed 8B stores).

template <bool BIAS, bool RESID, bool RELU, bool OUTBF16, int OUTMODE>
__global__ __launch_bounds__(256) void gemm64_kernel(
    const short* __restrict__ Ah, const short* __restrict__ Bh,
    const float* __restrict__ bias, const float* __restrict__ resid,
    void* __restrict__ outp, int M, int N, int K,
    unsigned short* __restrict__ vtp) {
  __shared__ short As[2][64 * 32];
  __shared__ short Bs[2][64 * 32];

  const int tid = threadIdx.x;
  const int lane = tid & 63;
  const int wid = tid >> 6;
  const int wr = (wid >> 1) << 5;  // 0 or 32
  const int wc = (wid & 1) << 5;   // 0 or 32
  const int l15 = lane & 15, lh = lane >> 4;

  const int gx = gridDim.x;
  const int lin = blockIdx.y * gx + blockIdx.x;
  const int nwg = gx * gridDim.y;
  const int nl = (lin & 7) * (nwg >> 3) + (lin >> 3);
  const int rowBase = (nl / gx) << 6;
  const int colBase = (nl % gx) << 6;

  const int sr = tid >> 2;
  const int sc = (tid & 3) << 3;
  const int soff = sr * 32 + sc;
  const short* Ag = Ah + (size_t)(rowBase + sr) * K + sc;
  const short* Bg = Bh + (size_t)(colBase + sr) * K + sc;

  f32x4 acc[2][2];
#pragma unroll
  for (int m = 0; m < 2; ++m)
#pragma unroll
    for (int n = 0; n < 2; ++n) acc[m][n] = (f32x4){0.f, 0.f, 0.f, 0.f};

  const int kT = K >> 5;
  {
    gld16(Ag, &As[0][soff]);
    gld16(Bg, &Bs[0][soff]);
  }

  for (int kt = 0; kt < kT; ++kt) {
    __syncthreads();
    const int cb = kt & 1;
    if (kt + 1 < kT) {
      const int nb = cb ^ 1;
      const int k0 = (kt + 1) << 5;
      gld16(Ag + k0, &As[nb][soff]);
      gld16(Bg + k0, &Bs[nb][soff]);
    }

    const short* Asb = As[cb];
    const short* Bsb = Bs[cb];
    bf16x8 af[2], bfr[2];
#pragma unroll
    for (int m = 0; m < 2; ++m)
      af[m] = *(const bf16x8*)&Asb[(wr + m * 16 + l15) * 32 + lh * 8];
#pragma unroll
    for (int n = 0; n < 2; ++n)
      bfr[n] = *(const bf16x8*)&Bsb[(wc + n * 16 + l15) * 32 + lh * 8];
#pragma unroll
    for (int m = 0; m < 2; ++m)
#pragma unroll
      for (int n = 0; n < 2; ++n)
        acc[m][n] = __builtin_amdgcn_mfma_f32_16x16x32_bf16(af[m], bfr[n], acc[m][n], 0, 0, 0);
  }

  const int prow = rowBase + wr + lh * 4;
  const int pcol = colBase + wc + l15;
#pragma unroll
  for (int m = 0; m < 2; ++m) {
#pragma unroll
    for (int n = 0; n < 2; ++n) {
      const int c = pcol + n * 16;
      if constexpr (OUTMODE == 2) {
        // V^T epilogue: pack the i-quad (consecutive s) into one 8B store
        const int head = c >> 6, dim = c & 63;
        const int r0_ = prow + m * 16;
        const int b = r0_ >> 10, s0 = r0_ & 1023;
        unsigned lo = ((unsigned)f2bf(acc[m][n][1]) << 16) | f2bf(acc[m][n][0]);
        unsigned hi2 = ((unsigned)f2bf(acc[m][n][3]) << 16) | f2bf(acc[m][n][2]);
        unsigned long long wv = ((unsigned long long)hi2 << 32) | lo;
        *(unsigned long long*)&vtp[(((size_t)(b * 16 + head)) * 64 + dim) * 1024 + s0] = wv;
      } else {
        float badd = 0.f;
        if constexpr (BIAS) badd = bias[c];
#pragma unroll
        for (int i = 0; i < 4; ++i) {
          const int r = prow + m * 16 + i;
          float v = acc[m][n][i] + badd;
          if constexpr (RESID) v += resid[(size_t)r * N + c];
          if constexpr (RELU) v = fmaxf(v, 0.f);
          if constexpr (OUTBF16)
            ((unsigned short*)outp)[(size_t)r * N + c] = f2bf(v);
          else
            ((float*)outp)[(size_t)r * N + c] = v;
        }
      }
    }
  }
}

// ---------------- attention: 32x32x16 MFMA flash, exp2 softmax ----------
// K(hi,lo) and V double-buffered in LDS (48KB), 3 blocks/CU (VGPR 88).

__global__ __launch_bounds__(256, 3) void attn_mfma_kernel(
    const short* __restrict__ qhi, const short* __restrict__ qlo,
    const short* __restrict__ khi, const short* __restrict__ klo,
    const short* __restrict__ vt, unsigned short* __restrict__ o,
    int S, int H) {
  __shared__ short Kh[2][64 * 64];
  __shared__ short Kl[2][64 * 64];
  __shared__ short Vs[2][64 * 64];

  const int tid = threadIdx.x, lane = tid & 63, wid = tid >> 6;
  const int l31 = lane & 31;
  const int hi = lane >> 5;
  const int blk = blockIdx.x;
  const int j = blk >> 3;
  const int bh = ((blk & 7) << 3) + (j & 7);
  const int q0 = (j >> 3) << 7;
  const size_t hbase = (size_t)bh * S * 64;

  const size_t qrow = hbase + (size_t)(q0 + wid * 32 + l31) * 64;
  bf16x8 qfh[4], qfl[4];
#pragma unroll
  for (int t = 0; t < 4; ++t) {
    qfh[t] = *(const bf16x8*)(qhi + qrow + t * 16 + hi * 8);
    qfl[t] = *(const bf16x8*)(qlo + qrow + t * 16 + hi * 8);
  }

  float m_run = -INFINITY, l_run = 0.f;
  f32x16 accO0, accO1;
#pragma unroll
  for (int r = 0; r < 16; ++r) { accO0[r] = 0.f; accO1[r] = 0.f; }

  const int r0 = tid >> 3, c0 = tid & 7;
  const int sw0 = ((c0 ^ (r0 & 7)) << 3);
  const int r1 = r0 + 32;
  const int sw1 = ((c0 ^ (r1 & 7)) << 3);

  const int nT = S >> 6;
  {
    gld16(khi + hbase + r0 * 64 + sw0, (char*)Kh[0] + tid * 16);
    gld16(khi + hbase + r1 * 64 + sw1, (char*)Kh[0] + tid * 16 + 4096);
    gld16(klo + hbase + r0 * 64 + sw0, (char*)Kl[0] + tid * 16);
    gld16(klo + hbase + r1 * 64 + sw1, (char*)Kl[0] + tid * 16 + 4096);
    gld16(vt + hbase + (size_t)r0 * S + sw0, (char*)Vs[0] + tid * 16);
    gld16(vt + hbase + (size_t)r1 * S + sw1, (char*)Vs[0] + tid * 16 + 4096);
  }

  for (int kt = 0; kt < nT; ++kt) {
    __syncthreads();
    const int cb = kt & 1;
    if (kt + 1 < nT) {
      const int nb = cb ^ 1;
      const size_t kb = hbase + (size_t)(kt + 1) * 64 * 64;
      gld16(khi + kb + r0 * 64 + sw0, (char*)Kh[nb] + tid * 16);
      gld16(khi + kb + r1 * 64 + sw1, (char*)Kh[nb] + tid * 16 + 4096);
      gld16(klo + kb + r0 * 64 + sw0, (char*)Kl[nb] + tid * 16);
      gld16(klo + kb + r1 * 64 + sw1, (char*)Kl[nb] + tid * 16 + 4096);
      const short* vg = vt + hbase + (size_t)(kt + 1) * 64;
      gld16(vg + (size_t)r0 * S + sw0, (char*)Vs[nb] + tid * 16);
      gld16(vg + (size_t)r1 * S + sw1, (char*)Vs[nb] + tid * 16 + 4096);
    }

    const short* KhB = Kh[cb];
    const short* KlB = Kl[cb];
    const short* VsB = Vs[cb];

    f32x16 sA, sB, sA2, sB2;
#pragma unroll
    for (int r = 0; r < 16; ++r) { sA[r] = 0.f; sB[r] = 0.f; sA2[r] = 0.f; sB2[r] = 0.f; }
    __builtin_amdgcn_s_setprio(1);
#pragma unroll
    for (int t = 0; t < 4; ++t) {
      const int cA = ((2 * t + hi) ^ (l31 & 7)) << 3;
      bf16x8 kh0 = *(const bf16x8*)&KhB[l31 * 64 + cA];
      bf16x8 kl0 = *(const bf16x8*)&KlB[l31 * 64 + cA];
      bf16x8 kh1 = *(const bf16x8*)&KhB[(32 + l31) * 64 + cA];
      bf16x8 kl1 = *(const bf16x8*)&KlB[(32 + l31) * 64 + cA];
      f32x16& dA = (t < 2) ? sA : sA2;
      f32x16& dB = (t < 2) ? sB : sB2;
      dA = __builtin_amdgcn_mfma_f32_32x32x16_bf16(kh0, qfh[t], dA, 0, 0, 0);
      dB = __builtin_amdgcn_mfma_f32_32x32x16_bf16(kh1, qfh[t], dB, 0, 0, 0);
      dA = __builtin_amdgcn_mfma_f32_32x32x16_bf16(kh0, qfl[t], dA, 0, 0, 0);
      dB = __builtin_amdgcn_mfma_f32_32x32x16_bf16(kh1, qfl[t], dB, 0, 0, 0);
      dA = __builtin_amdgcn_mfma_f32_32x32x16_bf16(kl0, qfh[t], dA, 0, 0, 0);
      dB = __builtin_amdgcn_mfma_f32_32x32x16_bf16(kl1, qfh[t], dB, 0, 0, 0);
    }
    __builtin_amdgcn_s_setprio(0);
#pragma unroll
    for (int r = 0; r < 16; ++r) { sA[r] += sA2[r]; sB[r] += sB2[r]; }

    float t8[8];
#pragma unroll
    for (int r = 0; r < 8; ++r)
      t8[r] = fmaxf(fmaxf(sA[2 * r], sA[2 * r + 1]),
                    fmaxf(sB[2 * r], sB[2 * r + 1]));
    float t4a = fmaxf(t8[0], t8[1]), t4b = fmaxf(t8[2], t8[3]);
    float t4c = fmaxf(t8[4], t8[5]), t4d = fmaxf(t8[6], t8[7]);
    float mt = fmaxf(fmaxf(t4a, t4b), fmaxf(t4c, t4d));
    {
      unsigned ma = __float_as_uint(mt), mb = ma;
      plswap(ma, mb);
      mt = fmaxf(__uint_as_float(ma), __uint_as_float(mb));
    }

    if (__any(mt > m_run + 11.5f)) {
      float mn = fmaxf(m_run, mt);
      float a = fexp2(m_run - mn);
      m_run = mn;
      l_run *= a;
#pragma unroll
      for (int r = 0; r < 16; ++r) {
        const int qq = (r & 3) + 8 * (r >> 2) + 4 * hi;
        float ar = __shfl(a, qq);
        accO0[r] *= ar;
        accO1[r] *= ar;
      }
    }

    float ls = 0.f;
#pragma unroll
    for (int r = 0; r < 16; ++r) {
      sA[r] = fexp2(sA[r] - m_run);
      sB[r] = fexp2(sB[r] - m_run);
      ls += sA[r] + sB[r];
    }
    l_run += ls;

    unsigned a0 = pack2t(sA[0], sA[1]), a1 = pack2t(sA[2], sA[3]);
    unsigned a2 = pack2t(sA[4], sA[5]), a3 = pack2t(sA[6], sA[7]);
    plswap(a0, a2);
    plswap(a1, a3);
    unsigned b0 = pack2t(sA[8], sA[9]), b1 = pack2t(sA[10], sA[11]);
    unsigned b2 = pack2t(sA[12], sA[13]), b3 = pack2t(sA[14], sA[15]);
    plswap(b0, b2);
    plswap(b1, b3);
    unsigned c0_ = pack2t(sB[0], sB[1]), c1_ = pack2t(sB[2], sB[3]);
    unsigned c2_ = pack2t(sB[4], sB[5]), c3_ = pack2t(sB[6], sB[7]);
    plswap(c0_, c2_);
    plswap(c1_, c3_);
    unsigned d0 = pack2t(sB[8], sB[9]), d1 = pack2t(sB[10], sB[11]);
    unsigned d2 = pack2t(sB[12], sB[13]), d3 = pack2t(sB[14], sB[15]);
    plswap(d0, d2);
    plswap(d1, d3);

    bf16x8 pf0, pf1, pf2, pf3;
    {
      unsigned w[4];
      w[0] = a0; w[1] = a1; w[2] = a2; w[3] = a3;
      pf0 = *(bf16x8*)w;
      w[0] = b0; w[1] = b1; w[2] = b2; w[3] = b3;
      pf1 = *(bf16x8*)w;
      w[0] = c0_; w[1] = c1_; w[2] = c2_; w[3] = c3_;
      pf2 = *(bf16x8*)w;
      w[0] = d0; w[1] = d1; w[2] = d2; w[3] = d3;
      pf3 = *(bf16x8*)w;
    }

    __builtin_amdgcn_s_setprio(1);
    {
      const int d1r = 32 + l31;
#pragma unroll
      for (int c = 0; c < 4; ++c) {
        bf16x8 bv0 = *(const bf16x8*)&VsB[l31 * 64 + ((((2 * c + hi)) ^ (l31 & 7)) << 3)];
        bf16x8 bv1 = *(const bf16x8*)&VsB[d1r * 64 + ((((2 * c + hi)) ^ (d1r & 7)) << 3)];
        bf16x8 pf = (c == 0) ? pf0 : (c == 1) ? pf1 : (c == 2) ? pf2 : pf3;
        accO0 = __builtin_amdgcn_mfma_f32_32x32x16_bf16(pf, bv0, accO0, 0, 0, 0);
        accO1 = __builtin_amdgcn_mfma_f32_32x32x16_bf16(pf, bv1, accO1, 0, 0, 0);
      }
    }
    __builtin_amdgcn_s_setprio(0);
  }

  {
    unsigned la = __float_as_uint(l_run), lb = la;
    plswap(la, lb);
    l_run = __uint_as_float(la) + __uint_as_float(lb);
  }
  float lrec = 1.0f / l_run;

  const int b = bh >> 4, h = bh & 15;
#pragma unroll
  for (int r = 0; r < 16; ++r) {
    const int qq = (r & 3) + 8 * (r >> 2) + 4 * hi;
    float rr = __shfl(lrec, qq);
    const size_t row = (size_t)(b * S + q0 + wid * 32 + qq) * 1024 + h * 64;
    o[row + l31] = f2bf(accO0[r] * rr);
    o[row + 32 + l31] = f2bf(accO1[r] * rr);
  }
}

// ---------------- launch ----------------

extern "C" void kernel_launch(void* const* d_in, const int* in_sizes, int n_in,
                              void* d_out, int out_size, void* d_ws,
                              size_t ws_size, hipStream_t stream) {
  const float* x = (const float*)d_in[0];
  const float* in_project = (const float*)d_in[1];
  const float* out_project = (const float*)d_in[2];
  const float* ln1_g = (const float*)d_in[3];
  const float* ln1_b = (const float*)d_in[4];
  const float* w_up = (const float*)d_in[5];
  const float* b_up = (const float*)d_in[6];
  const float* w_down = (const float*)d_in[7];
  const float* b_down = (const float*)d_in[8];
  const float* ln2_g = (const float*)d_in[9];
  const float* ln2_b = (const float*)d_in[10];

  const int B = in_sizes[0] / (1024 * 1024);
  const int S = 1024, H = 16;
  const int M = B * S;  // 4096

  char* ws = (char*)d_ws;
  short* h_hi = (short*)(ws + 0);                 // 8MB
  short* h_lo = (short*)(ws + 8388608);           // 8MB
  float* x2 = (float*)(ws + 0);                   // 16MB fp32, reuses h (dead)
  short* qhi = (short*)(ws + 16777216);           // 8MB
  short* qlo = (short*)(ws + 25165824);           // 8MB
  short* khi = (short*)(ws + 33554432);           // 8MB
  short* klo = (short*)(ws + 41943040);           // 8MB
  short* vt  = (short*)(ws + 50331648);           // 8MB
  short* o = (short*)(ws + 67108864);             // 8MB
  short* h2 = (short*)(ws + 75497472);            // 8MB
  short* u = (short*)(ws + 83886080);             // 16MB
  short* Wq_hi = (short*)(ws + 100663296);        // 6MB
  short* Wq_lo = (short*)(ws + 106954752);        // 6MB
  short* WoT = (short*)(ws + 113246208);          // 2MB
  short* WupT = (short*)(ws + 115343360);         // 4MB
  short* WdnT = (short*)(ws + 119537664);         // 4MB

  prep_kernel<<<10240, 256, 0, stream>>>(
      x, ln1_g, ln1_b, (unsigned short*)h_hi, (unsigned short*)h_lo,
      in_project, (unsigned short*)Wq_hi, (unsigned short*)Wq_lo,
      out_project, w_up, w_down, (unsigned short*)WoT, (unsigned short*)WupT,
      (unsigned short*)WdnT);

  // QK GEMM (split x3, N=2048, 128x128) -> q/k split bf16
  gemm_kernel<true, false, false, false, false, 1>
      <<<dim3(2048 / 128, M / 128), 256, 0, stream>>>(
          h_hi, h_lo, Wq_hi, Wq_lo, nullptr, nullptr, nullptr, M, 2048, 1024,
          (unsigned short*)qhi, (unsigned short*)qlo, (unsigned short*)khi,
          (unsigned short*)klo);

  // V GEMM (plain, N=1024, 64x64 -> 1024 blocks) -> v^T bf16
  gemm64_kernel<false, false, false, false, 2>
      <<<dim3(1024 / 64, M / 64), 256, 0, stream>>>(
          h_hi, Wq_hi + (size_t)2048 * 1024, nullptr, nullptr, nullptr,
          M, 1024, 1024, (unsigned short*)vt);

  attn_mfma_kernel<<<512, 256, 0, stream>>>(
      qhi, qlo, khi, klo, vt, (unsigned short*)o, S, H);

  // out-proj + residual x -> x2 fp32 (64x64)
  gemm64_kernel<false, true, false, false, 0>
      <<<dim3(1024 / 64, M / 64), 256, 0, stream>>>(
          o, WoT, nullptr, x, x2, M, 1024, 1024, nullptr);

  ln2_kernel<<<M, 256, 0, stream>>>(x2, ln2_g, ln2_b, (unsigned short*)h2);

  // FFN up (128x128)
  gemm_kernel<false, true, false, true, true, 0>
      <<<dim3(2048 / 128, M / 128), 256, 0, stream>>>(
          h2, nullptr, WupT, nullptr, b_up, nullptr, u, M, 2048, 1024,
          nullptr, nullptr, nullptr, nullptr);

  // FFN down + bias + residual x2 -> out fp32 (64x64)
  gemm64_kernel<true, true, false, false, 0>
      <<<dim3(1024 / 64, M / 64), 256, 0, stream>>>(
          u, WdnT, b_down, x2, d_out, M, 1024, 2048, nullptr);
}